// Round 12
// baseline (250.243 us; speedup 1.0000x reference)
//
#include <hip/hip_runtime.h>

#define N_NODES 50000
#define N_EDGES 800000
#define N_PADROWS 50048   // kept for buffer sizing

typedef unsigned int uint;
typedef unsigned short ushort;

typedef __attribute__((ext_vector_type(8))) short short8;
typedef __attribute__((ext_vector_type(4))) float floatx4;

__device__ __forceinline__ ushort f2bf(float f) {
    uint u = __builtin_bit_cast(uint, f);
    u += 0x7fffu + ((u >> 16) & 1u);      // round-to-nearest-even
    return (ushort)(u >> 16);
}
__device__ __forceinline__ float bf2f(ushort h) {
    uint u = ((uint)h) << 16;
    return __builtin_bit_cast(float, u);
}
__device__ __forceinline__ float bflo(uint w) { return __builtin_bit_cast(float, w << 16); }
__device__ __forceinline__ float bfhi(uint w) { return __builtin_bit_cast(float, w & 0xffff0000u); }
__device__ __forceinline__ uint pack2(float a, float b) {
    return (uint)f2bf(a) | ((uint)f2bf(b) << 16);
}

// ---------------- fused init: hist + conv (x->bf16) + weight prep ----------------
// counts zeroed by hipMemsetAsync before this kernel (stream-ordered).
// block ranges: [0,3125) hist, [3125,4688) conv, [4688,4848) prep
#define HIST_BLOCKS 3125
#define CONV_BLOCKS 1563
#define PREP_BLOCKS 160
#define INIT_BLOCKS (HIST_BLOCKS + CONV_BLOCKS + PREP_BLOCKS)

__global__ __launch_bounds__(256) void init_k(const int* __restrict__ ei,
                                              const float* __restrict__ x,
                                              ushort* __restrict__ hb,
                                              int* __restrict__ counts,
                                              const float* __restrict__ basis,
                                              const float* __restrict__ root,
                                              ushort* __restrict__ Bsw) {
    int b = blockIdx.x;
    if (b < HIST_BLOCKS) {
        int e = b * 256 + threadIdx.x;
        if (e < N_EDGES) atomicAdd(&counts[ei[N_EDGES + e]], 1);
    } else if (b < HIST_BLOCKS + CONV_BLOCKS) {
        // x fp32 -> dense bf16 [N][64], 8 floats per thread
        int i = (b - HIST_BLOCKS) * 256 + threadIdx.x;
        if (i >= N_NODES * 8) return;
        const float4* p = (const float4*)(x + (size_t)i * 8);
        float4 a = p[0], c = p[1];
        uint4 o;
        o.x = pack2(a.x, a.y); o.y = pack2(a.z, a.w);
        o.z = pack2(c.x, c.y); o.w = pack2(c.z, c.w);
        *(uint4*)(hb + (size_t)i * 8) = o;
    } else {
        // Bsw[l][kb][ct][q][n][j] = W_l[kb*32+q*8+j][ct*16+n], W_l = [basis_l ; root_l]
        int idx = (b - (HIST_BLOCKS + CONV_BLOCKS)) * 256 + threadIdx.x;
        if (idx >= 2 * 20480) return;
        int l = idx / 20480;
        int r = idx % 20480;
        int kb = r >> 11, ct = (r >> 9) & 3, q = (r >> 7) & 3, n = (r >> 3) & 15, j = r & 7;
        int k = kb * 32 + q * 8 + j;
        int c = ct * 16 + n;
        float v = (k < 256) ? basis[(size_t)l * 16384 + k * 64 + c]
                            : root[(size_t)l * 4096 + (k - 256) * 64 + c];
        Bsw[idx] = f2bf(v);
    }
}

// ---------------- CSR scan: ONE kernel ----------------
// Writes the LOCAL (per-1024-group) exclusive prefix to both lstart and cursor,
// plus per-group totals to bsums. The global group offset is recomputed by the
// consumers (scatter/aggemm) from bsums in-block — eliminates the scan3 dispatch.
// (round-10 lesson: 1-WG whole-scan = 126 µs on 1 CU; keep the 49-block form.)
__global__ __launch_bounds__(1024) void scan1_k(const int* __restrict__ counts,
                                                int* __restrict__ lstart,
                                                int* __restrict__ cursor,
                                                int* __restrict__ bsums) {
    __shared__ int s[1024];
    int i = blockIdx.x * 1024 + threadIdx.x;
    int x = (i < N_NODES) ? counts[i] : 0;
    s[threadIdx.x] = x;
    __syncthreads();
    for (int off = 1; off < 1024; off <<= 1) {
        int v = (threadIdx.x >= off) ? s[threadIdx.x - off] : 0;
        __syncthreads();
        s[threadIdx.x] += v;
        __syncthreads();
    }
    if (i < N_NODES) {
        int lp = s[threadIdx.x] - x;   // local exclusive prefix
        lstart[i] = lp;
        cursor[i] = lp;
    }
    if (threadIdx.x == 1023) bsums[blockIdx.x] = s[1023];
}

// single-pass scatter — round-1 proven core (1 edge/thread, max TLP), plus a
// per-block 49-entry bsums prefix table in LDS (wave 0, ~30 cy) so record
// position = local atomic slot + group offset. Grid is exactly 3125x256=800000.
// Scatter core FROZEN: bracketed at 47-50 µs by 4 failed structural attempts.
__global__ __launch_bounds__(256) void scatter_k(const int* __restrict__ ei,
                                                 const float* __restrict__ ea,
                                                 const float* __restrict__ att,   // [2,8,4]
                                                 const int* __restrict__ bsums,   // [49]
                                                 int* __restrict__ cursor,
                                                 uint4* __restrict__ rec) {
    __shared__ int pre_lds[64];
    if (threadIdx.x < 64) {
        int lane = threadIdx.x;
        int v = (lane < 49) ? bsums[lane] : 0;
        int x = v;
        #pragma unroll
        for (int off = 1; off < 64; off <<= 1) {
            int t = __shfl_up(x, off, 64);
            if (lane >= off) x += t;
        }
        pre_lds[lane] = x - v;   // exclusive group prefix
    }
    __syncthreads();

    int e = blockIdx.x * 256 + threadIdx.x;   // always < N_EDGES (exact grid)
    int src = ei[e];
    int dst = ei[N_EDGES + e];

    const float4* eav = (const float4*)(ea + (size_t)e * 8);
    float4 a0 = eav[0], a1 = eav[1];
    float ev[8] = {a0.x, a0.y, a0.z, a0.w, a1.x, a1.y, a1.z, a1.w};

    float4 c0 = make_float4(0.f, 0.f, 0.f, 0.f);
    float4 c1 = make_float4(0.f, 0.f, 0.f, 0.f);
    const float4* att0 = (const float4*)att;
    const float4* att1 = (const float4*)(att + 32);
    #pragma unroll
    for (int r = 0; r < 8; ++r) {
        float4 w0 = att0[r];
        float4 w1 = att1[r];
        c0.x = fmaf(ev[r], w0.x, c0.x); c0.y = fmaf(ev[r], w0.y, c0.y);
        c0.z = fmaf(ev[r], w0.z, c0.z); c0.w = fmaf(ev[r], w0.w, c0.w);
        c1.x = fmaf(ev[r], w1.x, c1.x); c1.y = fmaf(ev[r], w1.y, c1.y);
        c1.z = fmaf(ev[r], w1.z, c1.z); c1.w = fmaf(ev[r], w1.w, c1.w);
    }
    int pos = atomicAdd(&cursor[dst], 1) + pre_lds[dst >> 10];
    rec[2 * (size_t)pos]     = make_uint4((uint)src, pack2(c0.x, c0.y), pack2(c0.z, c0.w), 0u);
    rec[2 * (size_t)pos + 1] = make_uint4((uint)src, pack2(c1.x, c1.y), pack2(c1.z, c1.w), 0u);
}

// ---------------- fused per-layer aggregate + MFMA GEMM ----------------
// Round-7 proven core (251 µs wall). block = 16 nodes (grid 3125, exact).
// All 16 nodes share one scan1-group g = m0>>10 (16 | 1024, never crosses), so
// wave 0 computes the scalar group offset pre = sum(bsums[0..g-1]) and
// broadcasts; s = lstart[node] + pre. Phase A: wave wid aggregates nodes
// m0+wid*4..+3 into LDS y-tile [16][264] bf16; s/cnt/r.x readfirstlane'd ->
// scalar record loads + saddr hb gathers. (round-9: 16-wave variant regressed.)
// Phase B: wave wid owns output quadrant ct=wid.
__global__ __launch_bounds__(256) void aggemm_k(const int* __restrict__ lstart,
                                                const int* __restrict__ counts,
                                                const int* __restrict__ bsums,   // [49]
                                                const uint4* __restrict__ recs,  // rec (+1 for layer 1)
                                                const ushort* __restrict__ hb,   // [N][64] bf16 input
                                                const ushort* __restrict__ Bsw,  // [2560][8] bf16 frag order
                                                const float* __restrict__ bias,  // [64]
                                                float* __restrict__ outf,        // fp32 out or null
                                                ushort* __restrict__ outh,       // next hb or null
                                                int relu) {
    __shared__ __align__(16) ushort ylds[16][264];   // 8.25 KB; 16B-aligned for ds_read_b128
    __shared__ int pre_s;
    const int tid = threadIdx.x;
    const int lane = tid & 63;
    const int wid = tid >> 6;
    const int m0 = blockIdx.x * 16;

    // group offset for this block's 16 nodes (all share g)
    const int g = m0 >> 10;   // 0..48
    if (tid < 64) {
        int v = (lane < g) ? bsums[lane] : 0;
        #pragma unroll
        for (int off = 32; off > 0; off >>= 1) v += __shfl_xor(v, off, 64);
        if (lane == 0) pre_s = v;
    }
    __syncthreads();
    const int pre = pre_s;

    // ---- phase A: aggregate 4 nodes per wave ----
    for (int t = 0; t < 4; ++t) {
        int node = m0 + wid * 4 + t;
        int s   = __builtin_amdgcn_readfirstlane(lstart[node]) + pre;
        int cnt = __builtin_amdgcn_readfirstlane(counts[node]);
        float y0 = 0.f, y1 = 0.f, y2 = 0.f, y3 = 0.f;
        int j = 0;
        for (; j + 7 < cnt; j += 8) {
            uint4 r[8];
            #pragma unroll
            for (int i = 0; i < 8; ++i) r[i] = recs[2 * (size_t)(s + j + i)];
            float hv[8];
            #pragma unroll
            for (int i = 0; i < 8; ++i) {
                int srow = __builtin_amdgcn_readfirstlane((int)r[i].x);
                hv[i] = bf2f(hb[(size_t)srow * 64 + lane]);
            }
            #pragma unroll
            for (int i = 0; i < 8; ++i) {
                y0 = fmaf(bflo(r[i].y), hv[i], y0);
                y1 = fmaf(bfhi(r[i].y), hv[i], y1);
                y2 = fmaf(bflo(r[i].z), hv[i], y2);
                y3 = fmaf(bfhi(r[i].z), hv[i], y3);
            }
        }
        for (; j + 1 < cnt; j += 2) {
            uint4 ra = recs[2 * (size_t)(s + j)];
            uint4 rb = recs[2 * (size_t)(s + j + 1)];
            int sa = __builtin_amdgcn_readfirstlane((int)ra.x);
            int sb = __builtin_amdgcn_readfirstlane((int)rb.x);
            float ha = bf2f(hb[(size_t)sa * 64 + lane]);
            float hbv = bf2f(hb[(size_t)sb * 64 + lane]);
            y0 = fmaf(bflo(ra.y), ha, y0); y1 = fmaf(bfhi(ra.y), ha, y1);
            y2 = fmaf(bflo(ra.z), ha, y2); y3 = fmaf(bfhi(ra.z), ha, y3);
            y0 = fmaf(bflo(rb.y), hbv, y0); y1 = fmaf(bfhi(rb.y), hbv, y1);
            y2 = fmaf(bflo(rb.z), hbv, y2); y3 = fmaf(bfhi(rb.z), hbv, y3);
        }
        if (j < cnt) {
            uint4 r = recs[2 * (size_t)(s + j)];
            int sr = __builtin_amdgcn_readfirstlane((int)r.x);
            float hv = bf2f(hb[(size_t)sr * 64 + lane]);
            y0 = fmaf(bflo(r.y), hv, y0); y1 = fmaf(bfhi(r.y), hv, y1);
            y2 = fmaf(bflo(r.z), hv, y2); y3 = fmaf(bfhi(r.z), hv, y3);
        }
        int nl = wid * 4 + t;
        ylds[nl][lane]       = f2bf(y0);
        ylds[nl][64 + lane]  = f2bf(y1);
        ylds[nl][128 + lane] = f2bf(y2);
        ylds[nl][192 + lane] = f2bf(y3);
    }
    __syncthreads();

    // ---- phase B: MFMA, wave wid -> ct = wid ----
    const int nlo = lane & 15;
    const int quad = lane >> 4;
    const int ct = wid;
    floatx4 acc = (floatx4){0.f, 0.f, 0.f, 0.f};

    const ushort* hrow = hb + (size_t)(m0 + nlo) * 64 + quad * 8;
    #pragma unroll
    for (int kb = 0; kb < 10; ++kb) {
        short8 a;
        if (kb < 8) a = *(const short8*)&ylds[nlo][quad * 8 + kb * 32];
        else        a = __builtin_bit_cast(short8, *(const uint4*)(hrow + (kb - 8) * 32));
        short8 b = __builtin_bit_cast(short8, ((const uint4*)Bsw)[(kb * 4 + ct) * 64 + lane]);
        acc = __builtin_amdgcn_mfma_f32_16x16x32_bf16(a, b, acc, 0, 0, 0);
    }

    // C/D layout: col = ct*16 + (lane&15), row = quad*4 + reg
    int col = ct * 16 + nlo;
    float bv = bias[col];
    #pragma unroll
    for (int r = 0; r < 4; ++r) {
        int row = m0 + quad * 4 + r;   // < 50000 always (3125*16 exact)
        float v = acc[r] + bv;
        if (relu) v = fmaxf(v, 0.f);
        if (outf) outf[(size_t)row * 64 + col] = v;
        if (outh) outh[(size_t)row * 64 + col] = f2bf(v);
    }
}

// ---------------- launch ----------------

extern "C" void kernel_launch(void* const* d_in, const int* in_sizes, int n_in,
                              void* d_out, int out_size, void* d_ws, size_t ws_size,
                              hipStream_t stream) {
    const float* x     = (const float*)d_in[0];
    const int*   ei    = (const int*)d_in[1];
    const float* ea    = (const float*)d_in[2];
    const float* basis = (const float*)d_in[3];  // [2,4,64,64]
    const float* att   = (const float*)d_in[4];  // [2,8,4]
    const float* root  = (const float*)d_in[5];  // [2,64,64]
    const float* bias  = (const float*)d_in[6];  // [2,64]
    float* out = (float*)d_out;

    char* p = (char*)d_ws;
    uint4*  rec    = (uint4*)p;   p += (size_t)N_EDGES * 32;          // 25.6 MB
    ushort* hb0    = (ushort*)p;  p += (size_t)N_PADROWS * 64 * 2;    //  6.4 MB (x bf16)
    ushort* hb1    = (ushort*)p;  p += (size_t)N_PADROWS * 64 * 2;    //  6.4 MB (h1 bf16)
    ushort* Bsw    = (ushort*)p;  p += (size_t)2 * 20480 * 2;         //  80 KB
    int*    counts = (int*)p;     p += (size_t)N_NODES * 4;
    int*    lstart = (int*)p;     p += (size_t)N_NODES * 4;
    int*    cursor = (int*)p;     p += (size_t)N_NODES * 4;
    int*    bsums  = (int*)p;     p += 64 * 4;

    const int scan_blocks = (N_NODES + 1023) / 1024;  // 49

    hipMemsetAsync(counts, 0, (size_t)N_NODES * 4, stream);
    init_k<<<INIT_BLOCKS, 256, 0, stream>>>(ei, x, hb0, counts, basis, root, Bsw);
    scan1_k<<<scan_blocks, 1024, 0, stream>>>(counts, lstart, cursor, bsums);
    scatter_k<<<N_EDGES / 256, 256, 0, stream>>>(ei, ea, att, bsums, cursor, rec);

    dim3 f_grid(N_NODES / 16);   // 3125, exact

    // ---- layer 0: h = x (hb0) -> h1 bf16 (hb1) ----
    aggemm_k<<<f_grid, 256, 0, stream>>>(lstart, counts, bsums, rec, hb0, Bsw, bias, (float*)0, hb1, 1);

    // ---- layer 1: h = h1 (hb1) -> out fp32 ----
    aggemm_k<<<f_grid, 256, 0, stream>>>(lstart, counts, bsums, rec + 1, hb1, Bsw + 20480, bias + 64, out, (ushort*)0, 0);
}

// Round 14
// 223.313 us; speedup vs baseline: 1.1206x; 1.1206x over previous
//
#include <hip/hip_runtime.h>

#define N_NODES 50000
#define N_EDGES 800000
#define N_PADROWS 50048   // kept for buffer sizing

typedef unsigned int uint;
typedef unsigned short ushort;

typedef __attribute__((ext_vector_type(8))) short short8;
typedef __attribute__((ext_vector_type(4))) float floatx4;

__device__ __forceinline__ ushort f2bf(float f) {
    uint u = __builtin_bit_cast(uint, f);
    u += 0x7fffu + ((u >> 16) & 1u);      // round-to-nearest-even
    return (ushort)(u >> 16);
}
__device__ __forceinline__ float bf2f(ushort h) {
    uint u = ((uint)h) << 16;
    return __builtin_bit_cast(float, u);
}
__device__ __forceinline__ float bflo(uint w) { return __builtin_bit_cast(float, w << 16); }
__device__ __forceinline__ float bfhi(uint w) { return __builtin_bit_cast(float, w & 0xffff0000u); }
__device__ __forceinline__ uint pack2(float a, float b) {
    return (uint)f2bf(a) | ((uint)f2bf(b) << 16);
}

// ---------------- fused init: hist(+rank) + conv (x->bf16) + weight prep ----------------
// counts zeroed by hipMemsetAsync before this kernel (stream-ordered).
// hist stores the atomicAdd RETURN VALUE as rank[e] — the edge's slot within its
// dst node — so scatter needs NO atomics (pos = start[dst] + rank[e]).
// block ranges: [0,3125) hist, [3125,4688) conv, [4688,4848) prep
#define HIST_BLOCKS 3125
#define CONV_BLOCKS 1563
#define PREP_BLOCKS 160
#define INIT_BLOCKS (HIST_BLOCKS + CONV_BLOCKS + PREP_BLOCKS)

__global__ __launch_bounds__(256) void init_k(const int* __restrict__ ei,
                                              const float* __restrict__ x,
                                              ushort* __restrict__ hb,
                                              int* __restrict__ counts,
                                              int* __restrict__ rank,
                                              const float* __restrict__ basis,
                                              const float* __restrict__ root,
                                              ushort* __restrict__ Bsw) {
    int b = blockIdx.x;
    if (b < HIST_BLOCKS) {
        int e = b * 256 + threadIdx.x;   // always < N_EDGES (3125*256 exact)
        rank[e] = atomicAdd(&counts[ei[N_EDGES + e]], 1);
    } else if (b < HIST_BLOCKS + CONV_BLOCKS) {
        // x fp32 -> dense bf16 [N][64], 8 floats per thread
        int i = (b - HIST_BLOCKS) * 256 + threadIdx.x;
        if (i >= N_NODES * 8) return;
        const float4* p = (const float4*)(x + (size_t)i * 8);
        float4 a = p[0], c = p[1];
        uint4 o;
        o.x = pack2(a.x, a.y); o.y = pack2(a.z, a.w);
        o.z = pack2(c.x, c.y); o.w = pack2(c.z, c.w);
        *(uint4*)(hb + (size_t)i * 8) = o;
    } else {
        // Bsw[l][kb][ct][q][n][j] = W_l[kb*32+q*8+j][ct*16+n], W_l = [basis_l ; root_l]
        int idx = (b - (HIST_BLOCKS + CONV_BLOCKS)) * 256 + threadIdx.x;
        if (idx >= 2 * 20480) return;
        int l = idx / 20480;
        int r = idx % 20480;
        int kb = r >> 11, ct = (r >> 9) & 3, q = (r >> 7) & 3, n = (r >> 3) & 15, j = r & 7;
        int k = kb * 32 + q * 8 + j;
        int c = ct * 16 + n;
        float v = (k < 256) ? basis[(size_t)l * 16384 + k * 64 + c]
                            : root[(size_t)l * 4096 + (k - 256) * 64 + c];
        Bsw[idx] = f2bf(v);
    }
}

// ---------------- CSR scan (round-11 proven 2-kernel form) ----------------

__global__ __launch_bounds__(1024) void scan1_k(const int* __restrict__ counts,
                                                int* __restrict__ start,
                                                int* __restrict__ bsums) {
    __shared__ int s[1024];
    int i = blockIdx.x * 1024 + threadIdx.x;
    int x = (i < N_NODES) ? counts[i] : 0;
    s[threadIdx.x] = x;
    __syncthreads();
    for (int off = 1; off < 1024; off <<= 1) {
        int v = (threadIdx.x >= off) ? s[threadIdx.x - off] : 0;
        __syncthreads();
        s[threadIdx.x] += v;
        __syncthreads();
    }
    if (i < N_NODES) start[i] = s[threadIdx.x] - x;
    if (threadIdx.x == 1023) bsums[blockIdx.x] = s[1023];
}

// scan3 with scan2 folded in (round-11 proven): each 256-thread block spans one
// scan1-group g = blockIdx.x>>2; wave 0 sums bsums[0..g-1] and broadcasts.
// No cursor array anymore — rank-based scatter needs only start.
__global__ __launch_bounds__(256) void scan3_k(int* __restrict__ start,
                                               const int* __restrict__ bsums) {
    __shared__ int pre_s;
    const int g = blockIdx.x >> 2;        // 0..48
    if (threadIdx.x < 64) {
        int lane = threadIdx.x;
        int v = (lane < g) ? bsums[lane] : 0;
        #pragma unroll
        for (int off = 32; off > 0; off >>= 1) v += __shfl_xor(v, off, 64);
        if (lane == 0) pre_s = v;
    }
    __syncthreads();
    int i = blockIdx.x * 256 + threadIdx.x;
    if (i < N_NODES) start[i] += pre_s;
}

// single-pass scatter — round-1 proven core, ATOMIC-FREE: the slot was already
// reserved by init_k's histogram (rank[e]); pos = start[dst] + rank[e] is pure
// loads. Grid exactly 3125x256 = 800000. Store core FROZEN (random-line-bound).
__global__ __launch_bounds__(256) void scatter_k(const int* __restrict__ ei,
                                                 const float* __restrict__ ea,
                                                 const float* __restrict__ att,    // [2,8,4]
                                                 const int* __restrict__ start,
                                                 const int* __restrict__ rank,
                                                 uint4* __restrict__ rec) {
    int e = blockIdx.x * 256 + threadIdx.x;   // always < N_EDGES (exact grid)
    int src = ei[e];
    int dst = ei[N_EDGES + e];
    int rk  = rank[e];

    const float4* eav = (const float4*)(ea + (size_t)e * 8);
    float4 a0 = eav[0], a1 = eav[1];
    float ev[8] = {a0.x, a0.y, a0.z, a0.w, a1.x, a1.y, a1.z, a1.w};

    float4 c0 = make_float4(0.f, 0.f, 0.f, 0.f);
    float4 c1 = make_float4(0.f, 0.f, 0.f, 0.f);
    const float4* att0 = (const float4*)att;
    const float4* att1 = (const float4*)(att + 32);
    #pragma unroll
    for (int r = 0; r < 8; ++r) {
        float4 w0 = att0[r];
        float4 w1 = att1[r];
        c0.x = fmaf(ev[r], w0.x, c0.x); c0.y = fmaf(ev[r], w0.y, c0.y);
        c0.z = fmaf(ev[r], w0.z, c0.z); c0.w = fmaf(ev[r], w0.w, c0.w);
        c1.x = fmaf(ev[r], w1.x, c1.x); c1.y = fmaf(ev[r], w1.y, c1.y);
        c1.z = fmaf(ev[r], w1.z, c1.z); c1.w = fmaf(ev[r], w1.w, c1.w);
    }
    int pos = start[dst] + rk;
    rec[2 * (size_t)pos]     = make_uint4((uint)src, pack2(c0.x, c0.y), pack2(c0.z, c0.w), 0u);
    rec[2 * (size_t)pos + 1] = make_uint4((uint)src, pack2(c1.x, c1.y), pack2(c1.z, c1.w), 0u);
}

// ---------------- fused per-layer aggregate + MFMA GEMM ----------------
// EXACT round-11 proven form. block = 16 nodes (grid 3125, exact).
// Phase A: wave wid aggregates nodes m0+wid*4..+3 into LDS y-tile [16][264] bf16.
// s/cnt/r.x readfirstlane'd -> scalar record loads + saddr hb gathers.
// (round-9: 16-wave/1-node-per-wave variant regressed — TLP was not the limiter.)
// Phase B: wave wid owns output quadrant ct=wid.
__global__ __launch_bounds__(256) void aggemm_k(const int* __restrict__ start,
                                                const int* __restrict__ counts,
                                                const uint4* __restrict__ recs,  // rec (+1 for layer 1)
                                                const ushort* __restrict__ hb,   // [N][64] bf16 input
                                                const ushort* __restrict__ Bsw,  // [2560][8] bf16 frag order
                                                const float* __restrict__ bias,  // [64]
                                                float* __restrict__ outf,        // fp32 out or null
                                                ushort* __restrict__ outh,       // next hb or null
                                                int relu) {
    __shared__ __align__(16) ushort ylds[16][264];   // 8.25 KB; 16B-aligned for ds_read_b128
    const int tid = threadIdx.x;
    const int lane = tid & 63;
    const int wid = tid >> 6;
    const int m0 = blockIdx.x * 16;

    // ---- phase A: aggregate 4 nodes per wave ----
    for (int t = 0; t < 4; ++t) {
        int node = m0 + wid * 4 + t;
        int s   = __builtin_amdgcn_readfirstlane(start[node]);
        int cnt = __builtin_amdgcn_readfirstlane(counts[node]);
        float y0 = 0.f, y1 = 0.f, y2 = 0.f, y3 = 0.f;
        int j = 0;
        for (; j + 7 < cnt; j += 8) {
            uint4 r[8];
            #pragma unroll
            for (int i = 0; i < 8; ++i) r[i] = recs[2 * (size_t)(s + j + i)];
            float hv[8];
            #pragma unroll
            for (int i = 0; i < 8; ++i) {
                int srow = __builtin_amdgcn_readfirstlane((int)r[i].x);
                hv[i] = bf2f(hb[(size_t)srow * 64 + lane]);
            }
            #pragma unroll
            for (int i = 0; i < 8; ++i) {
                y0 = fmaf(bflo(r[i].y), hv[i], y0);
                y1 = fmaf(bfhi(r[i].y), hv[i], y1);
                y2 = fmaf(bflo(r[i].z), hv[i], y2);
                y3 = fmaf(bfhi(r[i].z), hv[i], y3);
            }
        }
        for (; j + 1 < cnt; j += 2) {
            uint4 ra = recs[2 * (size_t)(s + j)];
            uint4 rb = recs[2 * (size_t)(s + j + 1)];
            int sa = __builtin_amdgcn_readfirstlane((int)ra.x);
            int sb = __builtin_amdgcn_readfirstlane((int)rb.x);
            float ha = bf2f(hb[(size_t)sa * 64 + lane]);
            float hbv = bf2f(hb[(size_t)sb * 64 + lane]);
            y0 = fmaf(bflo(ra.y), ha, y0); y1 = fmaf(bfhi(ra.y), ha, y1);
            y2 = fmaf(bflo(ra.z), ha, y2); y3 = fmaf(bfhi(ra.z), ha, y3);
            y0 = fmaf(bflo(rb.y), hbv, y0); y1 = fmaf(bfhi(rb.y), hbv, y1);
            y2 = fmaf(bflo(rb.z), hbv, y2); y3 = fmaf(bfhi(rb.z), hbv, y3);
        }
        if (j < cnt) {
            uint4 r = recs[2 * (size_t)(s + j)];
            int sr = __builtin_amdgcn_readfirstlane((int)r.x);
            float hv = bf2f(hb[(size_t)sr * 64 + lane]);
            y0 = fmaf(bflo(r.y), hv, y0); y1 = fmaf(bfhi(r.y), hv, y1);
            y2 = fmaf(bflo(r.z), hv, y2); y3 = fmaf(bfhi(r.z), hv, y3);
        }
        int nl = wid * 4 + t;
        ylds[nl][lane]       = f2bf(y0);
        ylds[nl][64 + lane]  = f2bf(y1);
        ylds[nl][128 + lane] = f2bf(y2);
        ylds[nl][192 + lane] = f2bf(y3);
    }
    __syncthreads();

    // ---- phase B: MFMA, wave wid -> ct = wid ----
    const int nlo = lane & 15;
    const int quad = lane >> 4;
    const int ct = wid;
    floatx4 acc = (floatx4){0.f, 0.f, 0.f, 0.f};

    const ushort* hrow = hb + (size_t)(m0 + nlo) * 64 + quad * 8;
    #pragma unroll
    for (int kb = 0; kb < 10; ++kb) {
        short8 a;
        if (kb < 8) a = *(const short8*)&ylds[nlo][quad * 8 + kb * 32];
        else        a = __builtin_bit_cast(short8, *(const uint4*)(hrow + (kb - 8) * 32));
        short8 b = __builtin_bit_cast(short8, ((const uint4*)Bsw)[(kb * 4 + ct) * 64 + lane]);
        acc = __builtin_amdgcn_mfma_f32_16x16x32_bf16(a, b, acc, 0, 0, 0);
    }

    // C/D layout: col = ct*16 + (lane&15), row = quad*4 + reg
    int col = ct * 16 + nlo;
    float bv = bias[col];
    #pragma unroll
    for (int r = 0; r < 4; ++r) {
        int row = m0 + quad * 4 + r;   // < 50000 always (3125*16 exact)
        float v = acc[r] + bv;
        if (relu) v = fmaxf(v, 0.f);
        if (outf) outf[(size_t)row * 64 + col] = v;
        if (outh) outh[(size_t)row * 64 + col] = f2bf(v);
    }
}

// ---------------- launch ----------------

extern "C" void kernel_launch(void* const* d_in, const int* in_sizes, int n_in,
                              void* d_out, int out_size, void* d_ws, size_t ws_size,
                              hipStream_t stream) {
    const float* x     = (const float*)d_in[0];
    const int*   ei    = (const int*)d_in[1];
    const float* ea    = (const float*)d_in[2];
    const float* basis = (const float*)d_in[3];  // [2,4,64,64]
    const float* att   = (const float*)d_in[4];  // [2,8,4]
    const float* root  = (const float*)d_in[5];  // [2,64,64]
    const float* bias  = (const float*)d_in[6];  // [2,64]
    float* out = (float*)d_out;

    char* p = (char*)d_ws;
    uint4*  rec    = (uint4*)p;   p += (size_t)N_EDGES * 32;          // 25.6 MB
    ushort* hb0    = (ushort*)p;  p += (size_t)N_PADROWS * 64 * 2;    //  6.4 MB (x bf16)
    ushort* hb1    = (ushort*)p;  p += (size_t)N_PADROWS * 64 * 2;    //  6.4 MB (h1 bf16)
    ushort* Bsw    = (ushort*)p;  p += (size_t)2 * 20480 * 2;         //  80 KB
    int*    counts = (int*)p;     p += (size_t)N_NODES * 4;
    int*    start  = (int*)p;     p += (size_t)N_NODES * 4;
    int*    rank   = (int*)p;     p += (size_t)N_EDGES * 4;           //  3.2 MB
    int*    bsums  = (int*)p;     p += 64 * 4;

    const int scan_blocks = (N_NODES + 1023) / 1024;  // 49

    hipMemsetAsync(counts, 0, (size_t)N_NODES * 4, stream);
    init_k<<<INIT_BLOCKS, 256, 0, stream>>>(ei, x, hb0, counts, rank, basis, root, Bsw);
    scan1_k<<<scan_blocks, 1024, 0, stream>>>(counts, start, bsums);
    scan3_k<<<(N_NODES + 255) / 256, 256, 0, stream>>>(start, bsums);
    scatter_k<<<N_EDGES / 256, 256, 0, stream>>>(ei, ea, att, start, rank, rec);

    dim3 f_grid(N_NODES / 16);   // 3125, exact

    // ---- layer 0: h = x (hb0) -> h1 bf16 (hb1) ----
    aggemm_k<<<f_grid, 256, 0, stream>>>(start, counts, rec, hb0, Bsw, bias, (float*)0, hb1, 1);

    // ---- layer 1: h = h1 (hb1) -> out fp32 ----
    aggemm_k<<<f_grid, 256, 0, stream>>>(start, counts, rec + 1, hb1, Bsw + 20480, bias + 64, out, (ushort*)0, 0);
}